// Round 13
// baseline (16908.954 us; speedup 1.0000x reference)
//
#include <hip/hip_runtime.h>

typedef __attribute__((ext_vector_type(8))) short s8v;   // 8 bf16 MFMA frag
typedef __attribute__((ext_vector_type(4))) float f4v;   // MFMA acc / 4xf32
typedef __attribute__((ext_vector_type(4))) unsigned int u4v; // 16B copy
typedef unsigned long long u64;

__device__ __forceinline__ float bf2f(unsigned short u) {
    union { float f; unsigned int i; } v; v.i = ((unsigned int)u) << 16; return v.f;
}
__device__ __forceinline__ unsigned short f2bf(float f) {
    union { float f; unsigned int i; } v; v.f = f;
    unsigned int x = v.i;
    return (unsigned short)((x + 0x7fffu + ((x >> 16) & 1u)) >> 16); // RNE
}
__device__ __forceinline__ float ldf(const void* p, size_t i, int f32) {
    return f32 ? ((const float*)p)[i] : bf2f(((const unsigned short*)p)[i]);
}

// ---- agent-scope atomic data path (sc1/MALL — the ONLY path proven to cross
//      XCDs on this part: R4/R6/R10 passed; all alternatives failed) ----
__device__ __forceinline__ s8v ald16(u64* p) {
    union { s8v v; u64 u[2]; } r;
    r.u[0] = __hip_atomic_load(p,     __ATOMIC_RELAXED, __HIP_MEMORY_SCOPE_AGENT);
    r.u[1] = __hip_atomic_load(p + 1, __ATOMIC_RELAXED, __HIP_MEMORY_SCOPE_AGENT);
    return r.v;
}
// Pack 4 adjacent bf16 values (lanes an, an+16, an+32, an+48) into one qword;
// lanes 0..15 store it agent-coherently. Caller must be a FULL wave.
__device__ __forceinline__ void pack_store64(u64* p, int lane, unsigned short val) {
    unsigned int mv = val;
    unsigned int lo = mv | (__shfl_down(mv, 16, 64) << 16);
    unsigned int hi = __shfl_down(mv, 32, 64) | (__shfl_down(mv, 48, 64) << 16);
    if (lane < 16) {
        u64 q = (u64)lo | ((u64)hi << 32);
        __hip_atomic_store(p, q, __ATOMIC_RELAXED, __HIP_MEMORY_SCOPE_AGENT);
    }
}

// Relaxed poll (R6/R10-proven) + compiler-only fence pinning subsequent loads.
__device__ __forceinline__ void pollwait(int* f, int v) {
    while (__hip_atomic_load(f, __ATOMIC_RELAXED, __HIP_MEMORY_SCOPE_AGENT) < v)
        __builtin_amdgcn_s_sleep(1);
    __builtin_amdgcn_sched_barrier(0);
    asm volatile("" ::: "memory");
}

// ---------------- dtype detector + flag reset ----------------
// flags[0]: 1 if float arrays f32, 0 if bf16. flags[1]: reset encoding.
// flags[16..271] = flagA epochs (256), flags[272..527] = flagB epochs (256).
// Zeroed EVERY launch (graph-replay safe).
__global__ void detect_k(const unsigned short* __restrict__ xu,
                         const unsigned int* __restrict__ rw,
                         int* __restrict__ flags) {
    __shared__ int cnt;
    int tid = threadIdx.x;
    if (tid == 0) cnt = 0;
    for (int i = tid + 16; i < 528; i += 256) flags[i] = 0;
    __syncthreads();
    int bad = 0;
    for (int i = tid; i < 4096; i += 256) {
        unsigned short v = xu[i];
        int e = (v >> 7) & 0xFF;
        if (e == 0xFF || (e <= 90 && (v & 0x7FFFu) != 0)) bad++;
    }
    atomicAdd(&cnt, bad);
    __syncthreads();
    if (tid == 0) {
        flags[0] = (cnt > 16) ? 1 : 0;
        bool w01 = true, oddz = true, ones = false, b01 = true, h16 = true, fv = true;
        for (int i = 0; i < 32; ++i) {
            unsigned int w = rw[i];
            if (w > 1u) w01 = false;
            if ((i & 1) && w != 0u) oddz = false;
            if (w != 0u) ones = true;
            if ((w & 0xFFu) > 1u || ((w >> 8) & 0xFFu) > 1u ||
                ((w >> 16) & 0xFFu) > 1u || (w >> 24) > 1u) b01 = false;
            unsigned int lo = w & 0xFFFFu, hi = w >> 16;
            if (!((lo == 0u || lo == 0x3F80u) && (hi == 0u || hi == 0x3F80u))) h16 = false;
            if (!(w == 0u || w == 0x3F800000u)) fv = false;
        }
        int mode;
        if (w01 && oddz && ones) mode = 4;
        else if (w01) mode = 0;
        else if (fv) mode = 3;
        else if (h16) mode = 2;
        else if (b01) mode = 1;
        else mode = 0;
        flags[1] = mode;
    }
}

__device__ __forceinline__ int get_reset(const void* p, int mode, int idx) {
    switch (mode) {
        case 0: return ((const int*)p)[idx] != 0;
        case 1: return ((const signed char*)p)[idx] != 0;
        case 2: return ((const unsigned short*)p)[idx] != 0;
        case 3: return ((const float*)p)[idx] != 0.f;
        default: return ((const int*)p)[idx * 2] != 0;
    }
}

// stage 24 weight columns of a [1024][3072] matrix into lws rows 0..23
__device__ __forceinline__ void stage_w(const void* w, int wf32, int j0, int tid,
                                        unsigned short* lws) {
    for (int k = tid; k < 1024; k += 256) {
        #pragma unroll
        for (int g = 0; g < 3; ++g) {
            unsigned short tmp[8];
            size_t base = (size_t)k * 3072 + g * 1024 + j0;
            if (wf32) {
                const float* wf = (const float*)w;
                f4v v0 = *(const f4v*)&wf[base];
                f4v v1 = *(const f4v*)&wf[base + 4];
                #pragma unroll
                for (int r = 0; r < 4; ++r) { tmp[r] = f2bf(v0[r]); tmp[4 + r] = f2bf(v1[r]); }
            } else {
                union { u4v v; unsigned short u[8]; } cv;
                cv.v = *(const u4v*)&((const unsigned short*)w)[base];
                #pragma unroll
                for (int r = 0; r < 8; ++r) tmp[r] = cv.u[r];
            }
            #pragma unroll
            for (int r = 0; r < 8; ++r) lws[(g * 8 + r) * 1048 + k] = tmp[r];
        }
    }
}

// ---------------- persistent cooperative scan (R10 protocol + split poll) ----------------
// 128 blocks x 256 threads; block b owns h-dims j0=8b..8b+7. Per phase one
// 16x16 MFMA tile (M=batch=16), K=1024 split over 4 waves, LDS reduce.
// Reader-side pipelining: wave w's 64 flag entries [64w,64w+64) certify its
// K-slice in order — entries [64w,64w+32) = blocks 32w..32w+15 = dims kc 0..3,
// entries [64w+32,64w+64) = kc 4..7. Poll half1 -> issue kc0..3 loads ->
// poll half2 (loads fly underneath) -> issue kc4..7 -> MFMAs. Same flag set,
// same certificates, same writers as R10 — pure reader scheduling.
__global__ __launch_bounds__(256) void scan_k(
    const void* __restrict__ xv, const void* __restrict__ resetv,
    const void* __restrict__ carryv, const void* __restrict__ inithv,
    const void* __restrict__ wiv, const void* __restrict__ whv,
    const void* __restrict__ biasv, void* __restrict__ outv,
    unsigned short* __restrict__ hbuf0, unsigned short* __restrict__ hbuf1,
    unsigned short* __restrict__ rbuf0, unsigned short* __restrict__ rbuf1,
    int* __restrict__ flags) {
    __shared__ __align__(16) unsigned short lws[24 * 1048];
    __shared__ __align__(16) float lpartA[4 * 256];
    __shared__ __align__(16) float lpartB[4 * 256];
    __shared__ float lhe[128];

    const int xf32 = flags[0];
    const int rmode = flags[1];
    int* flagA = flags + 16;
    int* flagB = flags + 272;

    const int tid = threadIdx.x;
    const int wave = tid >> 6, lane = tid & 63;
    const int c = lane & 15, q = lane >> 4;   // MFMA lane roles
    const int j0 = blockIdx.x * 8;
    const int an = tid & 15, ac = tid >> 4;   // elementwise roles
    const int jloc = ac & 7, jg = j0 + jloc;
    const bool owner = (ac < 8);              // waves 0,1
    const int colA = owner ? jg : (1024 + jg);
    const int colB = 2048 + jg;
    const float biasA = ldf(biasv, colA, xf32);
    const float biasB = ldf(biasv, colB, xf32);
    const float initj = ldf(inithv, jg, xf32);
    const unsigned short initj_b = f2bf(initj);
    const int kbase = wave * 256;
    const int qidx = an * 256 + (j0 >> 2) + (wave & 1);
    const int ebase = wave * 64;              // this wave's flag-entry base
    const int eh1 = ebase + (lane & 31);      // half-1 entry (blocks 32w..32w+15)
    const int eh2 = ebase + 32 + (lane & 31); // half-2 entry (blocks 32w+16..32w+31)

    // ---- weights -> registers via LDS bounce ----
    s8v whA[8], whB[8], wiA[8], wiB[8];
    stage_w(whv, xf32, j0, tid, lws);
    __syncthreads();
    #pragma unroll
    for (int kc = 0; kc < 8; ++kc) {
        int kk = kbase + kc * 32 + q * 8;
        whA[kc] = *(const s8v*)&lws[c * 1048 + kk];
        whB[kc] = *(const s8v*)&lws[(16 + (c & 7)) * 1048 + kk];
    }
    __syncthreads();
    stage_w(wiv, xf32, j0, tid, lws);
    __syncthreads();
    #pragma unroll
    for (int kc = 0; kc < 8; ++kc) {
        int kk = kbase + kc * 32 + q * 8;
        wiA[kc] = *(const s8v*)&lws[c * 1048 + kk];
        wiB[kc] = *(const s8v*)&lws[(16 + (c & 7)) * 1048 + kk];
    }

    // x A-fragment registers + prefetch helper: A[m=batch=c][k]
    s8v xa[8];
    auto load_xa = [&](int tt) {
        if (xf32) {
            const float* xf = (const float*)xv;
            #pragma unroll
            for (int kc = 0; kc < 8; ++kc) {
                size_t b = (size_t)c * 1048576 + (size_t)tt * 1024 + kbase + kc * 32 + q * 8;
                f4v v0 = *(const f4v*)&xf[b];
                f4v v1 = *(const f4v*)&xf[b + 4];
                union { s8v v; unsigned short u[8]; } cv;
                #pragma unroll
                for (int r = 0; r < 4; ++r) { cv.u[r] = f2bf(v0[r]); cv.u[4 + r] = f2bf(v1[r]); }
                xa[kc] = cv.v;
            }
        } else {
            const unsigned short* xu = (const unsigned short*)xv;
            #pragma unroll
            for (int kc = 0; kc < 8; ++kc) {
                size_t b = (size_t)c * 1048576 + (size_t)tt * 1024 + kbase + kc * 32 + q * 8;
                xa[kc] = *(const s8v*)&xu[b];
            }
        }
    };

    // ---- h0 = reset[:,0] ? initial_h : carry[:,0,:]; third output ----
    float hreg = 0.f, zreg = 0.f, he_own = 0.f;
    int rs_cur = 0;
    if (owner) {
        rs_cur = get_reset(resetv, rmode, an * 1024);
        float h0 = rs_cur ? initj : ldf(carryv, (size_t)an * 1048576 + jg, xf32);
        unsigned short hb0 = f2bf(h0);
        hreg = bf2f(hb0);
        pack_store64((u64*)hbuf0 + qidx, lane, hb0);
        if (an == 0) {
            if (xf32) ((float*)outv)[(size_t)33554432 + jg] = initj;
            else ((unsigned short*)outv)[(size_t)33554432 + jg] = initj_b;
        }
        asm volatile("s_waitcnt vmcnt(0)" ::: "memory");
        if (lane == 0)
            __hip_atomic_store(&flagB[blockIdx.x * 2 + wave], 1,
                               __ATOMIC_RELAXED, __HIP_MEMORY_SCOPE_AGENT);
    }
    load_xa(0);

    for (int t = 0; t < 1024; ++t) {
        unsigned short* hcur = (t & 1) ? hbuf1 : hbuf0;
        unsigned short* hnxt = (t & 1) ? hbuf0 : hbuf1;
        unsigned short* rcur = (t & 1) ? rbuf1 : rbuf0;

        int rs_next = 0;
        if (owner) {
            he_own = rs_cur ? initj : hreg;
            lhe[an * 8 + jloc] = he_own;
            if (t < 1023) rs_next = get_reset(resetv, rmode, an * 1024 + t + 1);
        }

        // ===== Phase A =====
        // x-part accumulation BEFORE the polls (independent of h)
        f4v acc = (f4v){0.f, 0.f, 0.f, 0.f};
        #pragma unroll
        for (int kc = 0; kc < 8; ++kc)
            acc = __builtin_amdgcn_mfma_f32_16x16x32_bf16(xa[kc], wiA[kc], acc, 0, 0, 0);

        s8v ha[8];
        pollwait(&flagB[eh1], t + 1);     // certifies dims of kc 0..3
        #pragma unroll
        for (int kc = 0; kc < 4; ++kc)
            ha[kc] = ald16((u64*)hcur + ((c * 1024 + kbase + kc * 32 + q * 8) >> 2));
        pollwait(&flagB[eh2], t + 1);     // certifies kc 4..7; kc0..3 loads in flight
        #pragma unroll
        for (int kc = 4; kc < 8; ++kc)
            ha[kc] = ald16((u64*)hcur + ((c * 1024 + kbase + kc * 32 + q * 8) >> 2));
        #pragma unroll
        for (int kc = 0; kc < 8; ++kc)
            acc = __builtin_amdgcn_mfma_f32_16x16x32_bf16(ha[kc], whA[kc], acc, 0, 0, 0);
        *(f4v*)&lpartA[wave * 256 + c * 16 + q * 4] = acc;
        __syncthreads();
        {
            float pre = lpartA[ac * 16 + an] + lpartA[256 + ac * 16 + an] +
                        lpartA[512 + ac * 16 + an] + lpartA[768 + ac * 16 + an] + biasA;
            float sg = 1.f / (1.f + expf(-pre));
            if (owner) zreg = sg;
            else {
                pack_store64((u64*)rcur + qidx, lane, f2bf(sg * lhe[an * 8 + jloc]));
                asm volatile("s_waitcnt vmcnt(0)" ::: "memory");
                if (lane == 0)
                    __hip_atomic_store(&flagA[blockIdx.x * 2 + (wave - 2)], t + 1,
                                       __ATOMIC_RELAXED, __HIP_MEMORY_SCOPE_AGENT);
            }
        }

        // ===== Phase B =====
        f4v acc2 = (f4v){0.f, 0.f, 0.f, 0.f};
        #pragma unroll
        for (int kc = 0; kc < 8; ++kc)
            acc2 = __builtin_amdgcn_mfma_f32_16x16x32_bf16(xa[kc], wiB[kc], acc2, 0, 0, 0);

        s8v ra[8];
        pollwait(&flagA[eh1], t + 1);
        #pragma unroll
        for (int kc = 0; kc < 4; ++kc)
            ra[kc] = ald16((u64*)rcur + ((c * 1024 + kbase + kc * 32 + q * 8) >> 2));
        pollwait(&flagA[eh2], t + 1);
        #pragma unroll
        for (int kc = 4; kc < 8; ++kc)
            ra[kc] = ald16((u64*)rcur + ((c * 1024 + kbase + kc * 32 + q * 8) >> 2));
        #pragma unroll
        for (int kc = 0; kc < 8; ++kc)
            acc2 = __builtin_amdgcn_mfma_f32_16x16x32_bf16(ra[kc], whB[kc], acc2, 0, 0, 0);

        // issue next step's x loads now: xa(t) is dead, latency hides under
        // the reduce + publish + next poll
        if (t < 1023) load_xa(t + 1);

        *(f4v*)&lpartB[wave * 256 + c * 16 + q * 4] = acc2;
        __syncthreads();
        if (owner) {
            float preB = lpartB[ac * 16 + an] + lpartB[256 + ac * 16 + an] +
                         lpartB[512 + ac * 16 + an] + lpartB[768 + ac * 16 + an] + biasB;
            float aa = tanhf(preB);
            float hn = (1.f - zreg) * he_own + zreg * aa;
            unsigned short hb = f2bf(hn);
            hreg = hn;
            pack_store64((u64*)hnxt + qidx, lane, rs_next ? initj_b : hb);
            asm volatile("s_waitcnt vmcnt(0)" ::: "memory");
            if (lane == 0)
                __hip_atomic_store(&flagB[blockIdx.x * 2 + wave], t + 2,
                                   __ATOMIC_RELAXED, __HIP_MEMORY_SCOPE_AGENT);
            size_t oidx = ((size_t)an * 1024 + t) * 1024 + jg;
            if (xf32) {
                float* o = (float*)outv;
                o[oidx] = hn;
                o[16777216 + oidx] = hn;
            } else {
                unsigned short* o = (unsigned short*)outv;
                o[oidx] = hb;
                o[16777216 + oidx] = hb;
            }
            rs_cur = rs_next;
        }
    }
}

extern "C" void kernel_launch(void* const* d_in, const int* in_sizes, int n_in,
                              void* d_out, int out_size, void* d_ws, size_t ws_size,
                              hipStream_t stream) {
    const void* x     = d_in[0];
    const void* reset = d_in[1];
    const void* carry = d_in[2];
    const void* inith = d_in[3];
    const void* w_i   = d_in[4];
    const void* w_h   = d_in[5];
    const void* bias  = d_in[6];

    char* ws = (char*)d_ws;
    unsigned short* hbuf0 = (unsigned short*)ws;              // 32 KB
    unsigned short* hbuf1 = (unsigned short*)(ws + 32768);    // 32 KB
    unsigned short* rbuf0 = (unsigned short*)(ws + 65536);    // 32 KB
    unsigned short* rbuf1 = (unsigned short*)(ws + 98304);    // 32 KB
    int*            flags = (int*)(ws + 131072);              // meta + 2x256 flags

    detect_k<<<dim3(1), dim3(256), 0, stream>>>(
        (const unsigned short*)x, (const unsigned int*)reset, flags);

    void* kargs[] = { (void*)&x, (void*)&reset, (void*)&carry, (void*)&inith,
                      (void*)&w_i, (void*)&w_h, (void*)&bias, (void*)&d_out,
                      (void*)&hbuf0, (void*)&hbuf1, (void*)&rbuf0, (void*)&rbuf1,
                      (void*)&flags };
    hipError_t err = hipLaunchCooperativeKernel(
        reinterpret_cast<const void*>(&scan_k),
        dim3(128), dim3(256), kargs, 0, stream);
    (void)err; (void)in_sizes; (void)n_in; (void)out_size; (void)ws_size;
}

// Round 14
// 14439.450 us; speedup vs baseline: 1.1710x; 1.1710x over previous
//
#include <hip/hip_runtime.h>

typedef __attribute__((ext_vector_type(8))) short s8v;   // 8 bf16 MFMA frag
typedef __attribute__((ext_vector_type(4))) float f4v;   // MFMA acc / 4xf32
typedef __attribute__((ext_vector_type(4))) unsigned int u4v; // 16B copy
typedef unsigned long long u64;

__device__ __forceinline__ float bf2f(unsigned short u) {
    union { float f; unsigned int i; } v; v.i = ((unsigned int)u) << 16; return v.f;
}
__device__ __forceinline__ unsigned short f2bf(float f) {
    union { float f; unsigned int i; } v; v.f = f;
    unsigned int x = v.i;
    return (unsigned short)((x + 0x7fffu + ((x >> 16) & 1u)) >> 16); // RNE
}
__device__ __forceinline__ float ldf(const void* p, size_t i, int f32) {
    return f32 ? ((const float*)p)[i] : bf2f(((const unsigned short*)p)[i]);
}

// ---- agent-scope atomic data path (sc1/MALL — the ONLY path proven to cross
//      XCDs on this part: R4 and R6/R10 passed with it; volatile, plain-cached
//      and hand-asm variants all failed) ----
__device__ __forceinline__ s8v ald16(u64* p) {
    union { s8v v; u64 u[2]; } r;
    r.u[0] = __hip_atomic_load(p,     __ATOMIC_RELAXED, __HIP_MEMORY_SCOPE_AGENT);
    r.u[1] = __hip_atomic_load(p + 1, __ATOMIC_RELAXED, __HIP_MEMORY_SCOPE_AGENT);
    return r.v;
}
// Pack 4 adjacent bf16 values (lanes an, an+16, an+32, an+48) into one qword;
// lanes 0..15 store it agent-coherently. Caller must be a FULL wave.
__device__ __forceinline__ void pack_store64(u64* p, int lane, unsigned short val) {
    unsigned int mv = val;
    unsigned int lo = mv | (__shfl_down(mv, 16, 64) << 16);
    unsigned int hi = __shfl_down(mv, 32, 64) | (__shfl_down(mv, 48, 64) << 16);
    if (lane < 16) {
        u64 q = (u64)lo | ((u64)hi << 32);
        __hip_atomic_store(p, q, __ATOMIC_RELAXED, __HIP_MEMORY_SCOPE_AGENT);
    }
}

// Relaxed poll (R6/R10-proven) + compiler-only fence: sched_barrier + memory
// clobber pin the certified reads after the spin. Wave-AND semantics: each
// lane polls one flag entry; the wave exits only when ALL 64 lanes have seen
// their entry >= v, which covers exactly this wave's producer set.
__device__ __forceinline__ void pollwait(int* f, int v) {
    while (__hip_atomic_load(f, __ATOMIC_RELAXED, __HIP_MEMORY_SCOPE_AGENT) < v)
        __builtin_amdgcn_s_sleep(1);
    __builtin_amdgcn_sched_barrier(0);
    asm volatile("" ::: "memory");
}

// ---------------- dtype detector + flag reset ----------------
// flags[0]: 1 if float arrays f32, 0 if bf16. flags[1]: reset encoding.
// flags[16..271] = flagA epochs (256), flags[272..527] = flagB epochs (256).
// Zeroed EVERY launch (graph-replay safe).
__global__ void detect_k(const unsigned short* __restrict__ xu,
                         const unsigned int* __restrict__ rw,
                         int* __restrict__ flags) {
    __shared__ int cnt;
    int tid = threadIdx.x;
    if (tid == 0) cnt = 0;
    for (int i = tid + 16; i < 528; i += 256) flags[i] = 0;
    __syncthreads();
    int bad = 0;
    for (int i = tid; i < 4096; i += 256) {
        unsigned short v = xu[i];
        int e = (v >> 7) & 0xFF;
        if (e == 0xFF || (e <= 90 && (v & 0x7FFFu) != 0)) bad++;
    }
    atomicAdd(&cnt, bad);
    __syncthreads();
    if (tid == 0) {
        flags[0] = (cnt > 16) ? 1 : 0;
        bool w01 = true, oddz = true, ones = false, b01 = true, h16 = true, fv = true;
        for (int i = 0; i < 32; ++i) {
            unsigned int w = rw[i];
            if (w > 1u) w01 = false;
            if ((i & 1) && w != 0u) oddz = false;
            if (w != 0u) ones = true;
            if ((w & 0xFFu) > 1u || ((w >> 8) & 0xFFu) > 1u ||
                ((w >> 16) & 0xFFu) > 1u || (w >> 24) > 1u) b01 = false;
            unsigned int lo = w & 0xFFFFu, hi = w >> 16;
            if (!((lo == 0u || lo == 0x3F80u) && (hi == 0u || hi == 0x3F80u))) h16 = false;
            if (!(w == 0u || w == 0x3F800000u)) fv = false;
        }
        int mode;
        if (w01 && oddz && ones) mode = 4;
        else if (w01) mode = 0;
        else if (fv) mode = 3;
        else if (h16) mode = 2;
        else if (b01) mode = 1;
        else mode = 0;
        flags[1] = mode;
    }
}

__device__ __forceinline__ int get_reset(const void* p, int mode, int idx) {
    switch (mode) {
        case 0: return ((const int*)p)[idx] != 0;
        case 1: return ((const signed char*)p)[idx] != 0;
        case 2: return ((const unsigned short*)p)[idx] != 0;
        case 3: return ((const float*)p)[idx] != 0.f;
        default: return ((const int*)p)[idx * 2] != 0;
    }
}

// stage 24 weight columns of a [1024][3072] matrix into lws rows 0..23
__device__ __forceinline__ void stage_w(const void* w, int wf32, int j0, int tid,
                                        unsigned short* lws) {
    for (int k = tid; k < 1024; k += 256) {
        #pragma unroll
        for (int g = 0; g < 3; ++g) {
            unsigned short tmp[8];
            size_t base = (size_t)k * 3072 + g * 1024 + j0;
            if (wf32) {
                const float* wf = (const float*)w;
                f4v v0 = *(const f4v*)&wf[base];
                f4v v1 = *(const f4v*)&wf[base + 4];
                #pragma unroll
                for (int r = 0; r < 4; ++r) { tmp[r] = f2bf(v0[r]); tmp[4 + r] = f2bf(v1[r]); }
            } else {
                union { u4v v; unsigned short u[8]; } cv;
                cv.v = *(const u4v*)&((const unsigned short*)w)[base];
                #pragma unroll
                for (int r = 0; r < 8; ++r) tmp[r] = cv.u[r];
            }
            #pragma unroll
            for (int r = 0; r < 8; ++r) lws[(g * 8 + r) * 1048 + k] = tmp[r];
        }
    }
}

// ---------------- persistent cooperative scan (R10-proven protocol) ----------------
// 128 blocks x 256 threads; block b owns h-dims j0=8b..8b+7. Per phase one
// 16x16 MFMA tile (M=batch=16), K=1024 split over 4 waves, LDS reduce.
// Sync (per-wave flags, monotonic epochs, double-buffered h/rh):
//   phase A(t): x-part MFMAs FIRST (independent of h) -> poll flagB[tid]>=t+1
//               -> read hbuf[t&1] -> h MFMAs -> LDS reduce -> waves 2/3 pack rh
//               into rbuf[t&1], drain, publish flagA=t+1
//   phase B(t): x-part MFMAs FIRST -> poll flagA[tid]>=t+1 -> read rbuf[t&1]
//               -> MFMAs -> reduce -> waves 0/1 pack h(t+1) into hbuf[(t+1)&1],
//               drain, publish flagB=t+2; outputs after publish.
__global__ __launch_bounds__(256) void scan_k(
    const void* __restrict__ xv, const void* __restrict__ resetv,
    const void* __restrict__ carryv, const void* __restrict__ inithv,
    const void* __restrict__ wiv, const void* __restrict__ whv,
    const void* __restrict__ biasv, void* __restrict__ outv,
    unsigned short* __restrict__ hbuf0, unsigned short* __restrict__ hbuf1,
    unsigned short* __restrict__ rbuf0, unsigned short* __restrict__ rbuf1,
    int* __restrict__ flags) {
    __shared__ __align__(16) unsigned short lws[24 * 1048];
    __shared__ __align__(16) float lpartA[4 * 256];
    __shared__ __align__(16) float lpartB[4 * 256];
    __shared__ float lhe[128];

    const int xf32 = flags[0];
    const int rmode = flags[1];
    int* flagA = flags + 16;
    int* flagB = flags + 272;

    const int tid = threadIdx.x;
    const int wave = tid >> 6, lane = tid & 63;
    const int c = lane & 15, q = lane >> 4;   // MFMA lane roles
    const int j0 = blockIdx.x * 8;
    const int an = tid & 15, ac = tid >> 4;   // elementwise roles
    const int jloc = ac & 7, jg = j0 + jloc;
    const bool owner = (ac < 8);              // waves 0,1
    const int colA = owner ? jg : (1024 + jg);
    const int colB = 2048 + jg;
    const float biasA = ldf(biasv, colA, xf32);
    const float biasB = ldf(biasv, colB, xf32);
    const float initj = ldf(inithv, jg, xf32);
    const unsigned short initj_b = f2bf(initj);
    const int kbase = wave * 256;
    const int qidx = an * 256 + (j0 >> 2) + (wave & 1);

    // ---- weights -> registers via LDS bounce ----
    s8v whA[8], whB[8], wiA[8], wiB[8];
    stage_w(whv, xf32, j0, tid, lws);
    __syncthreads();
    #pragma unroll
    for (int kc = 0; kc < 8; ++kc) {
        int kk = kbase + kc * 32 + q * 8;
        whA[kc] = *(const s8v*)&lws[c * 1048 + kk];
        whB[kc] = *(const s8v*)&lws[(16 + (c & 7)) * 1048 + kk];
    }
    __syncthreads();
    stage_w(wiv, xf32, j0, tid, lws);
    __syncthreads();
    #pragma unroll
    for (int kc = 0; kc < 8; ++kc) {
        int kk = kbase + kc * 32 + q * 8;
        wiA[kc] = *(const s8v*)&lws[c * 1048 + kk];
        wiB[kc] = *(const s8v*)&lws[(16 + (c & 7)) * 1048 + kk];
    }

    // x A-fragment registers + prefetch helper: A[m=batch=c][k]
    s8v xa[8];
    auto load_xa = [&](int tt) {
        if (xf32) {
            const float* xf = (const float*)xv;
            #pragma unroll
            for (int kc = 0; kc < 8; ++kc) {
                size_t b = (size_t)c * 1048576 + (size_t)tt * 1024 + kbase + kc * 32 + q * 8;
                f4v v0 = *(const f4v*)&xf[b];
                f4v v1 = *(const f4v*)&xf[b + 4];
                union { s8v v; unsigned short u[8]; } cv;
                #pragma unroll
                for (int r = 0; r < 4; ++r) { cv.u[r] = f2bf(v0[r]); cv.u[4 + r] = f2bf(v1[r]); }
                xa[kc] = cv.v;
            }
        } else {
            const unsigned short* xu = (const unsigned short*)xv;
            #pragma unroll
            for (int kc = 0; kc < 8; ++kc) {
                size_t b = (size_t)c * 1048576 + (size_t)tt * 1024 + kbase + kc * 32 + q * 8;
                xa[kc] = *(const s8v*)&xu[b];
            }
        }
    };

    // ---- h0 = reset[:,0] ? initial_h : carry[:,0,:]; third output ----
    float hreg = 0.f, zreg = 0.f, he_own = 0.f;
    int rs_cur = 0;
    if (owner) {
        rs_cur = get_reset(resetv, rmode, an * 1024);
        float h0 = rs_cur ? initj : ldf(carryv, (size_t)an * 1048576 + jg, xf32);
        unsigned short hb0 = f2bf(h0);
        hreg = bf2f(hb0);
        pack_store64((u64*)hbuf0 + qidx, lane, hb0);
        if (an == 0) {
            if (xf32) ((float*)outv)[(size_t)33554432 + jg] = initj;
            else ((unsigned short*)outv)[(size_t)33554432 + jg] = initj_b;
        }
        asm volatile("s_waitcnt vmcnt(0)" ::: "memory");
        if (lane == 0)
            __hip_atomic_store(&flagB[blockIdx.x * 2 + wave], 1,
                               __ATOMIC_RELAXED, __HIP_MEMORY_SCOPE_AGENT);
    }
    load_xa(0);

    for (int t = 0; t < 1024; ++t) {
        unsigned short* hcur = (t & 1) ? hbuf1 : hbuf0;
        unsigned short* hnxt = (t & 1) ? hbuf0 : hbuf1;
        unsigned short* rcur = (t & 1) ? rbuf1 : rbuf0;

        int rs_next = 0;
        if (owner) {
            he_own = rs_cur ? initj : hreg;
            lhe[an * 8 + jloc] = he_own;
            if (t < 1023) rs_next = get_reset(resetv, rmode, an * 1024 + t + 1);
        }

        // ===== Phase A =====
        // x-part accumulation BEFORE the poll (independent of h)
        f4v acc = (f4v){0.f, 0.f, 0.f, 0.f};
        #pragma unroll
        for (int kc = 0; kc < 8; ++kc)
            acc = __builtin_amdgcn_mfma_f32_16x16x32_bf16(xa[kc], wiA[kc], acc, 0, 0, 0);

        pollwait(&flagB[tid], t + 1);
        s8v ha[8];
        #pragma unroll
        for (int kc = 0; kc < 8; ++kc)
            ha[kc] = ald16((u64*)hcur + ((c * 1024 + kbase + kc * 32 + q * 8) >> 2));
        #pragma unroll
        for (int kc = 0; kc < 8; ++kc)
            acc = __builtin_amdgcn_mfma_f32_16x16x32_bf16(ha[kc], whA[kc], acc, 0, 0, 0);
        *(f4v*)&lpartA[wave * 256 + c * 16 + q * 4] = acc;
        __syncthreads();
        {
            float pre = lpartA[ac * 16 + an] + lpartA[256 + ac * 16 + an] +
                        lpartA[512 + ac * 16 + an] + lpartA[768 + ac * 16 + an] + biasA;
            float sg = 1.f / (1.f + expf(-pre));
            if (owner) zreg = sg;
            else {
                pack_store64((u64*)rcur + qidx, lane, f2bf(sg * lhe[an * 8 + jloc]));
                asm volatile("s_waitcnt vmcnt(0)" ::: "memory");
                if (lane == 0)
                    __hip_atomic_store(&flagA[blockIdx.x * 2 + (wave - 2)], t + 1,
                                       __ATOMIC_RELAXED, __HIP_MEMORY_SCOPE_AGENT);
            }
        }

        // ===== Phase B =====
        // x-part accumulation BEFORE the poll (independent of rh)
        f4v acc2 = (f4v){0.f, 0.f, 0.f, 0.f};
        #pragma unroll
        for (int kc = 0; kc < 8; ++kc)
            acc2 = __builtin_amdgcn_mfma_f32_16x16x32_bf16(xa[kc], wiB[kc], acc2, 0, 0, 0);

        pollwait(&flagA[tid], t + 1);
        s8v ra[8];
        #pragma unroll
        for (int kc = 0; kc < 8; ++kc)
            ra[kc] = ald16((u64*)rcur + ((c * 1024 + kbase + kc * 32 + q * 8) >> 2));
        #pragma unroll
        for (int kc = 0; kc < 8; ++kc)
            acc2 = __builtin_amdgcn_mfma_f32_16x16x32_bf16(ra[kc], whB[kc], acc2, 0, 0, 0);
        *(f4v*)&lpartB[wave * 256 + c * 16 + q * 4] = acc2;
        __syncthreads();
        if (owner) {
            float preB = lpartB[ac * 16 + an] + lpartB[256 + ac * 16 + an] +
                         lpartB[512 + ac * 16 + an] + lpartB[768 + ac * 16 + an] + biasB;
            float aa = tanhf(preB);
            float hn = (1.f - zreg) * he_own + zreg * aa;
            unsigned short hb = f2bf(hn);
            hreg = hn;
            pack_store64((u64*)hnxt + qidx, lane, rs_next ? initj_b : hb);
            asm volatile("s_waitcnt vmcnt(0)" ::: "memory");
            if (lane == 0)
                __hip_atomic_store(&flagB[blockIdx.x * 2 + wave], t + 2,
                                   __ATOMIC_RELAXED, __HIP_MEMORY_SCOPE_AGENT);
            size_t oidx = ((size_t)an * 1024 + t) * 1024 + jg;
            if (xf32) {
                float* o = (float*)outv;
                o[oidx] = hn;
                o[16777216 + oidx] = hn;
            } else {
                unsigned short* o = (unsigned short*)outv;
                o[oidx] = hb;
                o[16777216 + oidx] = hb;
            }
            rs_cur = rs_next;
        }
        // prefetch next step's x fragments; latency hides under next poll
        if (t < 1023) load_xa(t + 1);
    }
}

extern "C" void kernel_launch(void* const* d_in, const int* in_sizes, int n_in,
                              void* d_out, int out_size, void* d_ws, size_t ws_size,
                              hipStream_t stream) {
    const void* x     = d_in[0];
    const void* reset = d_in[1];
    const void* carry = d_in[2];
    const void* inith = d_in[3];
    const void* w_i   = d_in[4];
    const void* w_h   = d_in[5];
    const void* bias  = d_in[6];

    char* ws = (char*)d_ws;
    unsigned short* hbuf0 = (unsigned short*)ws;              // 32 KB
    unsigned short* hbuf1 = (unsigned short*)(ws + 32768);    // 32 KB
    unsigned short* rbuf0 = (unsigned short*)(ws + 65536);    // 32 KB
    unsigned short* rbuf1 = (unsigned short*)(ws + 98304);    // 32 KB
    int*            flags = (int*)(ws + 131072);              // meta + 2x256 flags

    detect_k<<<dim3(1), dim3(256), 0, stream>>>(
        (const unsigned short*)x, (const unsigned int*)reset, flags);

    void* kargs[] = { (void*)&x, (void*)&reset, (void*)&carry, (void*)&inith,
                      (void*)&w_i, (void*)&w_h, (void*)&bias, (void*)&d_out,
                      (void*)&hbuf0, (void*)&hbuf1, (void*)&rbuf0, (void*)&rbuf1,
                      (void*)&flags };
    hipError_t err = hipLaunchCooperativeKernel(
        reinterpret_cast<const void*>(&scan_k),
        dim3(128), dim3(256), kargs, 0, stream);
    (void)err; (void)in_sizes; (void)n_in; (void)out_size; (void)ws_size;
}